// Round 1
// baseline (761.547 us; speedup 1.0000x reference)
//
#include <hip/hip_runtime.h>

// ---------------------------------------------------------------------------
// VectorQuantizer: N=16384 points x K=8192 codes x D=512 fp32.
// R8: score GEMM ported from the m97-style 128x128 2-barrier structure
// (27% MfmaUtil ceiling) to the 256x256 8-phase schedule with counted
// vmcnt (T3+T4), setprio around MFMA clusters (T5), on top of the existing
// verified XOR-swizzled LDS (T2, 0 bank conflicts). 8 waves (2Mx4N),
// BK=64, 128 KiB double-buffered LDS, 12 ds_read_b128 + 16 MFMA per phase,
// one quarter-tile staged per phase, steady-state s_waitcnt vmcnt(2).
// Each block handles its 512-code split as 2x256-code passes so the
// partials layout / gather kernel / margin+fp64-rescore machinery are
// byte-identical to the verified R7 kernel.
// Fallback (small ws): round-1 pure-fp32 VALU kernel (known-correct).
// ---------------------------------------------------------------------------

#define N_PTS   16384
#define DIM     512
#define K_CODES 8192
#define NSPLIT  16                    // code splits (512 codes each)
#define OUT0_N  (N_PTS * DIM)
#define NELEM_F (8388608.0f)
#define MARGIN  1.5e-2f

typedef _Float16 half8 __attribute__((ext_vector_type(8)));
typedef _Float16 f16x4 __attribute__((ext_vector_type(4)));
typedef float    f32x4 __attribute__((ext_vector_type(4)));

// fast-path workspace layout (bytes) — unchanged from R7
#define SZ_A3    (16384UL * 512 * 2)               // 16.8 MB
#define SZ_B3    (8192UL * 512 * 2)                // 8.4 MB
#define OFF_A3   0UL
#define OFF_B3   (OFF_A3 + SZ_A3)
#define OFF_CN   (OFF_B3 + SZ_B3)                  // cnorm 32 KB
#define OFF_PV1  (OFF_CN + 32768UL)
#define SZ_P     (16UL * 16384 * 4)                // 1 MB each
#define OFF_PI1  (OFF_PV1 + SZ_P)
#define OFF_PV2  (OFF_PI1 + SZ_P)
#define OFF_PI2  (OFF_PV2 + SZ_P)
#define OFF_PSUM (OFF_PI2 + SZ_P)                  // psums 64 KB
#define OFF_CNT  (OFF_PSUM + 65536UL)              // counts 32 KB
#define WS_NEED  (OFF_CNT + 32768UL)

#define GLOAD_LDS16(g, l) \
    __builtin_amdgcn_global_load_lds( \
        (const __attribute__((address_space(1))) unsigned int*)(g), \
        (__attribute__((address_space(3))) unsigned int*)(l), 16, 0, 0)

// ---------------------------------------------------------------- prep (fused)
__global__ __launch_bounds__(128) void prep_all(const float* __restrict__ z_e,
                                                const float* __restrict__ cb,
                                                _Float16* __restrict__ A3,
                                                _Float16* __restrict__ B3,
                                                float* __restrict__ cnorm,
                                                unsigned int* __restrict__ counts) {
    const int b = blockIdx.x;
    const int t = threadIdx.x;
    if (b < 64) counts[b * 128 + t] = 0u;
    if (b < N_PTS) {
        const long r = b;
        const int d = t * 4;
        const float4 v = *(const float4*)(z_e + r * DIM + d);
        f16x4 h;
        h[0] = (_Float16)v.x; h[1] = (_Float16)v.y;
        h[2] = (_Float16)v.z; h[3] = (_Float16)v.w;
        *(f16x4*)(A3 + r * 512 + d) = h;
    } else {
        const long r = b - N_PTS;
        const int d = t * 4;
        const float4 v = *(const float4*)(cb + r * DIM + d);
        f16x4 h;
        h[0] = (_Float16)v.x; h[1] = (_Float16)v.y;
        h[2] = (_Float16)v.z; h[3] = (_Float16)v.w;
        *(f16x4*)(B3 + r * 512 + d) = h;
        float s = v.x * v.x + v.y * v.y + v.z * v.z + v.w * v.w;
#pragma unroll
        for (int o = 32; o > 0; o >>= 1) s += __shfl_down(s, o, 64);
        __shared__ float red[2];
        if ((t & 63) == 0) red[t >> 6] = s;
        __syncthreads();
        if (t == 0) cnorm[r] = red[0] + red[1];
    }
}

// ---------------------------------------------------------------- cnorm (fallback)
__global__ __launch_bounds__(128) void cnorm_kernel(const float* __restrict__ cb,
                                                    float* __restrict__ cnorm) {
    const int k = blockIdx.x;
    const int t = threadIdx.x;
    const float4 v = *(const float4*)(cb + (size_t)k * DIM + t * 4);
    float s = v.x * v.x + v.y * v.y + v.z * v.z + v.w * v.w;
#pragma unroll
    for (int o = 32; o > 0; o >>= 1) s += __shfl_down(s, o, 64);
    __shared__ float red[2];
    if ((t & 63) == 0) red[t >> 6] = s;
    __syncthreads();
    if (t == 0) cnorm[k] = red[0] + red[1];
}

// ---------------------------------------------------------------- top2 merge
// merges candidate pair (c1,d1,c2,d2) into running (a1,b1,a2,b2);
// comparator identical to the harness-verified R7 merge (lowest k on ties).
__device__ __forceinline__ void top2_merge(float& a1, int& b1, float& a2, int& b2,
                                           const float c1, const int d1,
                                           const float c2, const int d2) {
    if (c1 < a1 || (c1 == a1 && d1 < b1)) {
        if (a1 < c2 || (a1 == c2 && b1 < d2)) { a2 = a1; b2 = b1; }
        else { a2 = c2; b2 = d2; }
        a1 = c1; b1 = d1;
    } else {
        if (c1 < a2 || (c1 == a2 && d1 < b2)) { a2 = c1; b2 = d1; }
    }
}

// ---------------------------------------------------------------- score GEMM
// 256x256 tile, BK=64, 512 threads = 8 waves (2Mx4N), each wave 128x64 via
// 8x4 of 16x16x32 f16 MFMA. LDS: 2 bufs x (A 32KB + B 32KB) = 128 KiB,
// row-major [256][64] halves with 16B-chunk XOR swizzle:
//   LDS[r][c] = G[r][c ^ (r&7)]   (stage pre-swizzles the GLOBAL source,
//   read XORs the chunk; verified 0 bank conflicts in R4-R7).
// Staging unit = quarter tile (64 rows = 1 global_load_lds/thread).
// Phase = quadrant (4mi x 2ni) x K=64: 12 ds_read_b128 + 16 MFMA.
// Stage schedule per group g (tile t=g, reads buf g&1):
//   p1: A1,A3(g+1)  p2: B0,B1(g+1)  p3: B2,B3(g+1)  p4: A0,A2(g+2)
//   (A0/A2 of buf g&1 are last read in p2 -> safe to overwrite from p3 on;
//    B quarters are read by their wn-wave in every phase -> only staged into
//    the buffer NOT being read.)
// vmcnt(2) once per K-tile at p4 (steady), vmcnt(0) at g==6 (drain), none g==7.
__global__ __launch_bounds__(512, 2) void score_kernel(
    const _Float16* __restrict__ A3, const _Float16* __restrict__ B3,
    const float* __restrict__ cnorm,
    float* __restrict__ pv1, int* __restrict__ pi1,
    float* __restrict__ pv2, int* __restrict__ pi2) {
    __shared__ _Float16 smem[65536];    // 128 KiB

    const int tid = threadIdx.x;
    const int w   = tid >> 6;           // wave 0..7
    const int l   = tid & 63;
    const int wm  = w >> 2;             // 0..1
    const int wn  = w & 3;              // 0..3
    const int m16 = l & 15;
    const int qq  = l >> 4;
    const int x7  = l & 7;
    const int pbase  = blockIdx.x * 256;
    const int nsplit = blockIdx.y;      // 0..15

    // staging: thread -> (row tid>>3, linear chunk tid&7) of a 64-row quarter;
    // global source chunk pre-swizzled so LDS[r][c] = G[r][c^(r&7)].
    const int srow = tid >> 3;          // 0..63
    const int sc   = ((tid & 7) ^ (srow & 7)) * 8;        // halves
    const _Float16* gA = A3 + (size_t)(pbase + srow) * 512 + sc;

    // read-side bases
    const int rA = wm * 128 + m16;      // A row base (+ mi*16)
    const int rB = wn * 64  + m16;      // B row base (+ ni*16)
    const int k0 = (qq ^ x7) * 8;       // ks=0 chunk offset (halves); ks=1 -> ^32

#define STAGE_A(q, tau) \
    GLOAD_LDS16(gA + (q) * 64 * 512 + (tau) * 64, \
                &smem[(((tau) & 1) * 32768) + (q) * 4096 + w * 512])
#define STAGE_B(q, tau) \
    GLOAD_LDS16(gB + (q) * 64 * 512 + (tau) * 64, \
                &smem[(((tau) & 1) * 32768) + 16384 + (q) * 4096 + w * 512])

#define PHASE(mh, nh, STAGE_STMT, VM_STMT) do {                                 \
    half8 af[4][2]; half8 bf[2][2];                                             \
    _Pragma("unroll")                                                           \
    for (int i_ = 0; i_ < 4; ++i_) {                                            \
        const int r_ = (rA + ((mh) * 4 + i_) * 16) * 64;                        \
        af[i_][0] = *(const half8*)&smem[bufo + r_ + k0];                       \
        af[i_][1] = *(const half8*)&smem[bufo + r_ + (k0 ^ 32)];                \
    }                                                                           \
    _Pragma("unroll")                                                           \
    for (int j_ = 0; j_ < 2; ++j_) {                                            \
        const int r_ = (rB + ((nh) * 2 + j_) * 16) * 64;                        \
        bf[j_][0] = *(const half8*)&smem[bufo + 16384 + r_ + k0];               \
        bf[j_][1] = *(const half8*)&smem[bufo + 16384 + r_ + (k0 ^ 32)];        \
    }                                                                           \
    STAGE_STMT;                                                                 \
    __builtin_amdgcn_s_barrier();                                               \
    asm volatile("s_waitcnt lgkmcnt(0)" ::: "memory");                          \
    __builtin_amdgcn_sched_barrier(0);                                          \
    __builtin_amdgcn_s_setprio(1);                                              \
    _Pragma("unroll")                                                           \
    for (int i_ = 0; i_ < 4; ++i_)                                              \
        _Pragma("unroll")                                                       \
        for (int j_ = 0; j_ < 2; ++j_) {                                        \
            acc[(mh) * 4 + i_][(nh) * 2 + j_] =                                 \
                __builtin_amdgcn_mfma_f32_16x16x32_f16(                         \
                    af[i_][0], bf[j_][0], acc[(mh) * 4 + i_][(nh) * 2 + j_],    \
                    0, 0, 0);                                                   \
            acc[(mh) * 4 + i_][(nh) * 2 + j_] =                                 \
                __builtin_amdgcn_mfma_f32_16x16x32_f16(                         \
                    af[i_][1], bf[j_][1], acc[(mh) * 4 + i_][(nh) * 2 + j_],    \
                    0, 0, 0);                                                   \
        }                                                                       \
    __builtin_amdgcn_s_setprio(0);                                              \
    VM_STMT;                                                                    \
    __builtin_amdgcn_s_barrier();                                               \
    __builtin_amdgcn_sched_barrier(0);                                          \
} while (0)

    // running per-point top2 across the two 256-code passes (threads 0..255)
    float rv1 = 3.0e38f, rv2 = 3.0e38f;
    int   ri1 = 0x7fffffff, ri2 = 0x7fffffff;

    // epilogue scratch overlay on buf0 A region (16 KB; reused between passes)
    float* sc1 = (float*)smem;
    float* sc2 = sc1 + 1024;
    int*   si1 = (int*)(sc2 + 1024);
    int*   si2 = si1 + 1024;

#pragma unroll 1
    for (int nt = 0; nt < 2; ++nt) {
        const int kbase = nsplit * 512 + nt * 256;
        const _Float16* gB = B3 + (size_t)(kbase + srow) * 512 + sc;

        f32x4 acc[8][4];
#pragma unroll
        for (int mi = 0; mi < 8; ++mi)
#pragma unroll
            for (int ni = 0; ni < 4; ++ni)
                acc[mi][ni] = (f32x4){0.f, 0.f, 0.f, 0.f};

        // ---- prologue: tile0 fully + A0/A2 of tile1 stay in flight
        STAGE_A(0, 0); STAGE_A(2, 0); STAGE_A(1, 0); STAGE_A(3, 0);
        STAGE_B(0, 0); STAGE_B(1, 0); STAGE_B(2, 0); STAGE_B(3, 0);
        STAGE_A(0, 1); STAGE_A(2, 1);
        asm volatile("s_waitcnt vmcnt(2)" ::: "memory");
        __builtin_amdgcn_s_barrier();
        __builtin_amdgcn_sched_barrier(0);

#pragma unroll 1
        for (int g = 0; g < 8; ++g) {
            const int bufo = (g & 1) * 32768;
            PHASE(0, 0,
                  { if (g < 7) { STAGE_A(1, g + 1); STAGE_A(3, g + 1); } },
                  {});
            PHASE(0, 1,
                  { if (g < 7) { STAGE_B(0, g + 1); STAGE_B(1, g + 1); } },
                  {});
            PHASE(1, 0,
                  { if (g < 7) { STAGE_B(2, g + 1); STAGE_B(3, g + 1); } },
                  {});
            PHASE(1, 1,
                  { if (g < 6) { STAGE_A(0, g + 2); STAGE_A(2, g + 2); } },
                  { if (g < 6) asm volatile("s_waitcnt vmcnt(2)" ::: "memory");
                    else if (g == 6) asm volatile("s_waitcnt vmcnt(0)" ::: "memory"); });
        }

        // ---- fold: scores -> per-lane top2-of-4(ni) -> 16-lane merge -> LDS
        const int kb2 = kbase + wn * 64;
        float cn[4];
#pragma unroll
        for (int ni = 0; ni < 4; ++ni) cn[ni] = cnorm[kb2 + ni * 16 + m16];

#pragma unroll
        for (int mi = 0; mi < 8; ++mi) {
#pragma unroll
            for (int r = 0; r < 4; ++r) {
                float a1 = 3.0e38f, a2 = 3.0e38f;
                int   b1 = 0x7fffffff, b2 = 0x7fffffff;
#pragma unroll
                for (int ni = 0; ni < 4; ++ni) {      // k ascending: lowest wins ties
                    const float s = fmaf(-2.0f, acc[mi][ni][r], cn[ni]);
                    const int k = kb2 + ni * 16 + m16;
                    if (s < a1) { a2 = a1; b2 = b1; a1 = s; b1 = k; }
                    else if (s < a2) { a2 = s; b2 = k; }
                }
#pragma unroll
                for (int m = 1; m < 16; m <<= 1) {
                    const float c1 = __shfl_xor(a1, m, 64);
                    const int   d1 = __shfl_xor(b1, m, 64);
                    const float c2 = __shfl_xor(a2, m, 64);
                    const int   d2 = __shfl_xor(b2, m, 64);
                    top2_merge(a1, b1, a2, b2, c1, d1, c2, d2);
                }
                if ((l & 15) == 0) {
                    const int pr = wm * 128 + mi * 16 + qq * 4 + r;   // 0..255
                    sc1[pr * 4 + wn] = a1; si1[pr * 4 + wn] = b1;
                    sc2[pr * 4 + wn] = a2; si2[pr * 4 + wn] = b2;
                }
            }
        }
        __syncthreads();
        if (tid < 256) {
            float a1 = sc1[tid * 4], a2 = sc2[tid * 4];
            int   b1 = si1[tid * 4], b2 = si2[tid * 4];
#pragma unroll
            for (int gg = 1; gg < 4; ++gg)
                top2_merge(a1, b1, a2, b2, sc1[tid * 4 + gg], si1[tid * 4 + gg],
                           sc2[tid * 4 + gg], si2[tid * 4 + gg]);
            top2_merge(rv1, ri1, rv2, ri2, a1, b1, a2, b2);
        }
        __syncthreads();   // scratch reads done before next pass re-stages buf0
    }

    if (tid < 256) {
        const size_t o = (size_t)nsplit * N_PTS + pbase + tid;
        pv1[o] = rv1; pi1[o] = ri1;
        pv2[o] = rv2; pi2[o] = ri2;
    }
#undef STAGE_A
#undef STAGE_B
#undef PHASE
}

// ---------------------------------------------------------------- gather
// UNCHANGED from R7 (verified): parallel split merge + fp64 rescore of
// near-ties + fused gather/histogram/loss.
__global__ __launch_bounds__(128) void gather_kernel(
    const float* __restrict__ z_e, const float* __restrict__ cb,
    const float* __restrict__ pv1, const int* __restrict__ pi1,
    const float* __restrict__ pv2, const int* __restrict__ pi2,
    float* __restrict__ out_q, float* __restrict__ out_idx,
    unsigned int* __restrict__ counts, float* __restrict__ psums) {
    const int p = blockIdx.x;
    const int t = threadIdx.x;

    __shared__ float sv1[NSPLIT], sv2[NSPLIT];
    __shared__ int   si1[NSPLIT], si2[NSPLIT];
    if (t < NSPLIT) {
        const size_t o = (size_t)t * N_PTS + p;
        sv1[t] = pv1[o]; si1[t] = pi1[o];
        sv2[t] = pv2[o]; si2[t] = pi2[o];
    }
    __syncthreads();

    float bv = 3.0e38f; int bi = 0x7fffffff;
#pragma unroll
    for (int s = 0; s < NSPLIT; ++s) {
        const float v = sv1[s];
        const int i = si1[s];
        if (v < bv || (v == bv && i < bi)) { bv = v; bi = i; }
    }
    float second = 3.0e38f;
    int cand[8]; int nc = 1; cand[0] = bi;
#pragma unroll
    for (int s = 0; s < NSPLIT; ++s) {
        const float v = sv1[s];
        const int i = si1[s];
        const float w2 = sv2[s];
        const int j = si2[s];
        if (i != bi) {
            if (v < second) second = v;
            if (v <= bv + MARGIN && nc < 8) cand[nc++] = i;
        }
        if (j != bi) {
            if (w2 < second) second = w2;
            if (w2 <= bv + MARGIN && nc < 8) cand[nc++] = j;
        }
    }

    __shared__ double dred[2];
    if (second - bv <= MARGIN && nc > 1) {     // block-uniform condition
        double bestv = 1.0e300; int besti = 0x7fffffff;
        for (int c = 0; c < nc; ++c) {
            const int k = cand[c];
            double part = 0.0;
#pragma unroll
            for (int j = 0; j < 4; ++j) {
                const int d = t * 4 + j;
                const double cv = (double)cb[(size_t)k * DIM + d];
                const double zv = (double)z_e[(size_t)p * DIM + d];
                part += cv * cv - 2.0 * zv * cv;
            }
#pragma unroll
            for (int o = 32; o > 0; o >>= 1) part += __shfl_down(part, o, 64);
            if ((t & 63) == 0) dred[t >> 6] = part;
            __syncthreads();
            const double s = dred[0] + dred[1];
            __syncthreads();
            if (s < bestv || (s == bestv && k < besti)) { bestv = s; besti = k; }
        }
        bi = besti;
    }

    const float4 z = *(const float4*)(z_e + (size_t)p * DIM + t * 4);
    const float4 c = *(const float4*)(cb + (size_t)bi * DIM + t * 4);
    float4 d, o;
    d.x = c.x - z.x; d.y = c.y - z.y; d.z = c.z - z.z; d.w = c.w - z.w;
    o.x = z.x + d.x; o.y = z.y + d.y; o.z = z.z + d.z; o.w = z.w + d.w;
    *(float4*)(out_q + (size_t)p * DIM + t * 4) = o;
    float ls = d.x * d.x + d.y * d.y + d.z * d.z + d.w * d.w;
#pragma unroll
    for (int off = 32; off > 0; off >>= 1) ls += __shfl_down(ls, off, 64);
    __shared__ float red[2];
    if ((t & 63) == 0) red[t >> 6] = ls;
    __syncthreads();
    if (t == 0) {
        psums[p] = red[0] + red[1];
        out_idx[p] = (float)bi;
        atomicAdd(&counts[bi], 1u);
    }
}

// ---------------------------------------------------------------- finalize
__global__ __launch_bounds__(256) void finalize_kernel(
    const unsigned int* __restrict__ counts, const float* __restrict__ psums,
    float* __restrict__ out_scalars) {
    const int t = threadIdx.x;
    float ent = 0.0f;
    for (int b = t; b < K_CODES; b += 256) {
        const float pr = (float)counts[b] * (1.0f / 16384.0f);
        ent += pr * logf(pr + 1e-10f);
    }
    float ss = 0.0f;
    for (int i = t; i < N_PTS; i += 256) ss += psums[i];
#pragma unroll
    for (int off = 32; off > 0; off >>= 1) {
        ent += __shfl_down(ent, off, 64);
        ss += __shfl_down(ss, off, 64);
    }
    __shared__ float re[4], rs[4];
    if ((t & 63) == 0) { re[t >> 6] = ent; rs[t >> 6] = ss; }
    __syncthreads();
    if (t == 0) {
        const float loss = (rs[0] + rs[1] + rs[2] + rs[3]) * (1.0f / NELEM_F);
        out_scalars[0] = loss;
        out_scalars[1] = loss;
        out_scalars[2] = expf(-(re[0] + re[1] + re[2] + re[3]));
    }
}

// ================================================================ fallback
// round-1 pure fp32 path (used only if ws_size < WS_NEED)
#define FB_SPLIT 4
#define FB_KS    (K_CODES / FB_SPLIT)
#define FB_MT    128
#define FB_KT    128
#define FB_DT    32
#define FB_PITCH 36

__global__ __launch_bounds__(256, 2) void fb_dist_argmin_kernel(
    const float* __restrict__ z_e, const float* __restrict__ cb,
    const float* __restrict__ cnorm,
    float* __restrict__ pmin, int* __restrict__ pidx) {
    __shared__ float xs[FB_MT * FB_PITCH];
    __shared__ float cs[FB_KT * FB_PITCH];
    const int tid = threadIdx.x;
    const int tx = tid & 15, ty = tid >> 4;
    const int pbase = blockIdx.x * FB_MT;
    const int kbase0 = blockIdx.y * FB_KS;
    const int scol = (tid & 7) * 4, srow0 = tid >> 3;
    float mn[8], acc[8][8];
    int mi[8];
#pragma unroll
    for (int i = 0; i < 8; ++i) { mn[i] = 3.0e38f; mi[i] = 0; }
    for (int kt = 0; kt < FB_KS / FB_KT; ++kt) {
        const int kbase = kbase0 + kt * FB_KT;
#pragma unroll
        for (int i = 0; i < 8; ++i)
#pragma unroll
            for (int j = 0; j < 8; ++j) acc[i][j] = 0.0f;
        for (int dc = 0; dc < DIM / FB_DT; ++dc) {
            const int dbase = dc * FB_DT;
            __syncthreads();
#pragma unroll
            for (int it = 0; it < 4; ++it) {
                const int row = srow0 + it * 32;
                *(float4*)(xs + row * FB_PITCH + scol) =
                    *(const float4*)(z_e + (size_t)(pbase + row) * DIM + dbase + scol);
                *(float4*)(cs + row * FB_PITCH + scol) =
                    *(const float4*)(cb + (size_t)(kbase + row) * DIM + dbase + scol);
            }
            __syncthreads();
#pragma unroll 2
            for (int dd = 0; dd < FB_DT; dd += 4) {
                float4 xv[8], cv[8];
#pragma unroll
                for (int i = 0; i < 8; ++i)
                    xv[i] = *(const float4*)(xs + (ty + 16 * i) * FB_PITCH + dd);
#pragma unroll
                for (int j = 0; j < 8; ++j)
                    cv[j] = *(const float4*)(cs + (tx + 16 * j) * FB_PITCH + dd);
#pragma unroll
                for (int i = 0; i < 8; ++i)
#pragma unroll
                    for (int j = 0; j < 8; ++j)
                        acc[i][j] += xv[i].x * cv[j].x + xv[i].y * cv[j].y +
                                     xv[i].z * cv[j].z + xv[i].w * cv[j].w;
            }
        }
#pragma unroll
        for (int j = 0; j < 8; ++j) {
            const int k = kbase + tx + 16 * j;
            const float cn = cnorm[k];
#pragma unroll
            for (int i = 0; i < 8; ++i) {
                const float s = cn - 2.0f * acc[i][j];
                if (s < mn[i]) { mn[i] = s; mi[i] = k; }
            }
        }
    }
    float* rmin = xs;
    int* ridx = (int*)cs;
    __syncthreads();
#pragma unroll
    for (int i = 0; i < 8; ++i) {
        const int p = ty + 16 * i;
        rmin[p * 16 + tx] = mn[i];
        ridx[p * 16 + tx] = mi[i];
    }
    __syncthreads();
    if (tid < FB_MT) {
        float best = rmin[tid * 16];
        int bi = ridx[tid * 16];
#pragma unroll
        for (int t = 1; t < 16; ++t) {
            const float v = rmin[tid * 16 + t];
            const int k2 = ridx[tid * 16 + t];
            if (v < best || (v == best && k2 < bi)) { best = v; bi = k2; }
        }
        pmin[(size_t)blockIdx.y * N_PTS + pbase + tid] = best;
        pidx[(size_t)blockIdx.y * N_PTS + pbase + tid] = bi;
    }
}

__global__ __launch_bounds__(128) void fb_gather_kernel(
    const float* __restrict__ z_e, const float* __restrict__ cb,
    const float* __restrict__ pmin, const int* __restrict__ pidx,
    float* __restrict__ out_q, float* __restrict__ out_idx,
    unsigned int* __restrict__ counts, float* __restrict__ psums) {
    const int p = blockIdx.x;
    const int t = threadIdx.x;
    float best = pmin[p];
    int bi = pidx[p];
#pragma unroll
    for (int s = 1; s < FB_SPLIT; ++s) {
        const float v = pmin[(size_t)s * N_PTS + p];
        const int k2 = pidx[(size_t)s * N_PTS + p];
        if (v < best || (v == best && k2 < bi)) { best = v; bi = k2; }
    }
    const float4 z = *(const float4*)(z_e + (size_t)p * DIM + t * 4);
    const float4 c = *(const float4*)(cb + (size_t)bi * DIM + t * 4);
    float4 d, o;
    d.x = c.x - z.x; d.y = c.y - z.y; d.z = c.z - z.z; d.w = c.w - z.w;
    o.x = z.x + d.x; o.y = z.y + d.y; o.z = z.z + d.z; o.w = z.w + d.w;
    *(float4*)(out_q + (size_t)p * DIM + t * 4) = o;
    float ls = d.x * d.x + d.y * d.y + d.z * d.z + d.w * d.w;
#pragma unroll
    for (int off = 32; off > 0; off >>= 1) ls += __shfl_down(ls, off, 64);
    __shared__ float red[2];
    if ((t & 63) == 0) red[t >> 6] = ls;
    __syncthreads();
    if (t == 0) {
        psums[p] = red[0] + red[1];
        out_idx[p] = (float)bi;
        atomicAdd(&counts[bi], 1u);
    }
}

// ================================================================ launch
extern "C" void kernel_launch(void* const* d_in, const int* in_sizes, int n_in,
                              void* d_out, int out_size, void* d_ws, size_t ws_size,
                              hipStream_t stream) {
    const float* z_e = (const float*)d_in[0];
    const float* cb  = (const float*)d_in[1];
    float* out = (float*)d_out;
    char* ws = (char*)d_ws;

    if (ws_size >= WS_NEED) {
        _Float16* A3      = (_Float16*)(ws + OFF_A3);
        _Float16* B3      = (_Float16*)(ws + OFF_B3);
        float* cnorm      = (float*)(ws + OFF_CN);
        float* pv1        = (float*)(ws + OFF_PV1);
        int* pi1          = (int*)(ws + OFF_PI1);
        float* pv2        = (float*)(ws + OFF_PV2);
        int* pi2          = (int*)(ws + OFF_PI2);
        float* psums      = (float*)(ws + OFF_PSUM);
        unsigned int* cnt = (unsigned int*)(ws + OFF_CNT);

        prep_all<<<N_PTS + K_CODES, 128, 0, stream>>>(z_e, cb, A3, B3, cnorm, cnt);
        dim3 g(N_PTS / 256, NSPLIT);                   // 64 x 16 blocks, 512 thr
        score_kernel<<<g, 512, 0, stream>>>(A3, B3, cnorm, pv1, pi1, pv2, pi2);
        gather_kernel<<<N_PTS, 128, 0, stream>>>(z_e, cb, pv1, pi1, pv2, pi2,
                                                 out, out + OUT0_N, cnt, psums);
        finalize_kernel<<<1, 256, 0, stream>>>(cnt, psums, out + OUT0_N + N_PTS);
    } else {
        // round-1 fp32 fallback (<700 KB ws)
        float* cnorm      = (float*)ws;
        float* pmin       = (float*)(ws + 32768);
        int* pidx         = (int*)(ws + 32768 + 262144);
        unsigned int* cnt = (unsigned int*)(ws + 32768 + 2 * 262144);
        float* psums      = (float*)(ws + 32768 + 2 * 262144 + 32768);

        hipMemsetAsync(cnt, 0, 32768, stream);
        cnorm_kernel<<<K_CODES, 128, 0, stream>>>(cb, cnorm);
        dim3 grid1(N_PTS / FB_MT, FB_SPLIT);
        fb_dist_argmin_kernel<<<grid1, 256, 0, stream>>>(z_e, cb, cnorm, pmin, pidx);
        fb_gather_kernel<<<N_PTS, 128, 0, stream>>>(z_e, cb, pmin, pidx,
                                                    out, out + OUT0_N, cnt, psums);
        finalize_kernel<<<1, 256, 0, stream>>>(cnt, psums, out + OUT0_N + N_PTS);
    }
}